// Round 6
// baseline (530.088 us; speedup 1.0000x reference)
//
#include <hip/hip_runtime.h>

// Round-9. R5 landed the 3-kernel structure (496us total; fine=268, final~85,
// ~140 fixed). gather_fine is latency*MLP bound: 0.437 lines/cyc/CU with only
// 8 outstanding gathers/wave (the q-loop serializes the two points: lerp+store
// between the two 8-load batches); implied loaded L2 latency ~494cyc.
// This round: issue all 16 gathers (both points) back-to-back before any lerp
// (MLP 8->16, __launch_bounds__(256,8) caps VGPR at 64 to hold occupancy),
// and in final_kernel hoist the 9 independent ws stream-reads above the l2-6
// gather loop so they overlap gather latency.

#define TSIZE (1u << 19)
#define HMASK (TSIZE - 1u)
#define P1 2654435761u
#define P2 805459861u

typedef float f32x4 __attribute__((ext_vector_type(4)));
typedef float f32x2 __attribute__((ext_vector_type(2)));

__constant__ float RES_C[16] = {16.f, 20.f, 25.f, 32.f, 40.f, 50.f, 64.f, 80.f,
                                101.f, 128.f, 161.f, 203.f, 256.f, 322.f, 406.f, 512.f};

// dense-copy geometry for levels 0,1 (x in [0,1) -> coords in [res/2, res])
#define L0_LO 8
#define L0_DIM 9            // 729 entries
#define L1_LO 10
#define L1_DIM 11           // 1331 entries
#define NDENSE (729 + 1331) // 2060 float2 = 16480 B

__device__ __forceinline__ void hash_corners(const float halfr,
                                             const float px, const float py, const float pz,
                                             unsigned h[8],
                                             float& wx, float& wy, float& wz)
{
    const float fx = px * halfr, fy = py * halfr, fz = pz * halfr;
    const float bx = floorf(fx), by = floorf(fy), bz = floorf(fz);
    wx = fx - bx; wy = fy - by; wz = fz - bz;

    const unsigned ix0 = (unsigned)(int)bx;              // * prime 1
    const unsigned iy0 = (unsigned)(int)by * P1;
    const unsigned iz0 = (unsigned)(int)bz * P2;
    const unsigned ix1 = ix0 + 1u, iy1 = iy0 + P1, iz1 = iz0 + P2;

    h[0] = (ix0 ^ iy0 ^ iz0) & HMASK;
    h[1] = (ix0 ^ iy0 ^ iz1) & HMASK;
    h[2] = (ix0 ^ iy1 ^ iz0) & HMASK;
    h[3] = (ix0 ^ iy1 ^ iz1) & HMASK;
    h[4] = (ix1 ^ iy0 ^ iz0) & HMASK;
    h[5] = (ix1 ^ iy0 ^ iz1) & HMASK;
    h[6] = (ix1 ^ iy1 ^ iz0) & HMASK;
    h[7] = (ix1 ^ iy1 ^ iz1) & HMASK;
}

// v order: 000,001,010,011,100,101,110,111
__device__ __forceinline__ f32x2 trilerp(const float2 v[8],
                                         const float wx, const float wy, const float wz)
{
    const float c00a = v[0].x + wx * (v[4].x - v[0].x);
    const float c00b = v[0].y + wx * (v[4].y - v[0].y);
    const float c01a = v[1].x + wx * (v[5].x - v[1].x);
    const float c01b = v[1].y + wx * (v[5].y - v[1].y);
    const float c10a = v[2].x + wx * (v[6].x - v[2].x);
    const float c10b = v[2].y + wx * (v[6].y - v[2].y);
    const float c11a = v[3].x + wx * (v[7].x - v[3].x);
    const float c11b = v[3].y + wx * (v[7].y - v[3].y);

    const float c0a = c00a + wy * (c10a - c00a);
    const float c0b = c00b + wy * (c10b - c00b);
    const float c1a = c01a + wy * (c11a - c01a);
    const float c1b = c01b + wy * (c11b - c01b);

    f32x2 r = { c0a + wz * (c1a - c0a), c0b + wz * (c1b - c0b) };
    return r;
}

__device__ __forceinline__ void gather_lerp(const float2* __restrict__ tab,
                                            const float fx, const float fy, const float fz,
                                            float& ra, float& rb)
{
    unsigned h[8]; float wx, wy, wz;
    hash_corners(1.0f, fx, fy, fz, h, wx, wy, wz);   // caller pre-scales
    float2 v[8];
#pragma unroll
    for (int i = 0; i < 8; ++i) v[i] = tab[h[i]];
    f32x2 r = trilerp(v, wx, wy, wz);
    ra = r.x; rb = r.y;
}

// LDS dense trilinear (levels 0,1): identical math, dense [iz][iy][ix] layout.
__device__ __forceinline__ void dense_lerp(const float2* __restrict__ base,
                                           const int lo, const int d,
                                           const float fx, const float fy, const float fz,
                                           float& ra, float& rb)
{
    const float bx = floorf(fx), by = floorf(fy), bz = floorf(fz);
    const float wx = fx - bx, wy = fy - by, wz = fz - bz;
    const int ix = (int)bx - lo, iy = (int)by - lo, iz = (int)bz - lo;
    const int i000 = (iz * d + iy) * d + ix;

    float2 v[8];
    v[0] = base[i000];
    v[1] = base[i000 + d * d];
    v[2] = base[i000 + d];
    v[3] = base[i000 + d * d + d];
    v[4] = base[i000 + 1];
    v[5] = base[i000 + d * d + 1];
    v[6] = base[i000 + d + 1];
    v[7] = base[i000 + d * d + d + 1];

    f32x2 r = trilerp(v, wx, wy, wz);
    ra = r.x; rb = r.y;
}

// ---------------- prep: de-hash levels 0-1 into dense ws copy ----------------
__global__ __launch_bounds__(256) void prep_dense_kernel(
    const float* __restrict__ tables, float2* __restrict__ dense)
{
    const int i = blockIdx.x * 256 + threadIdx.x;
    const float2* __restrict__ tab = (const float2*)tables;
    if (i < 729) {
        const int ix = i % 9, iy = (i / 9) % 9, iz = i / 81;
        const unsigned h = ((unsigned)(ix + L0_LO)) ^
                           ((unsigned)(iy + L0_LO) * P1) ^
                           ((unsigned)(iz + L0_LO) * P2);
        dense[i] = tab[h & HMASK];                          // level 0
    } else if (i < NDENSE) {
        const int c = i - 729;
        const int ix = c % 11, iy = (c / 11) % 11, iz = c / 121;
        const unsigned h = ((unsigned)(ix + L1_LO)) ^
                           ((unsigned)(iy + L1_LO) * P1) ^
                           ((unsigned)(iz + L1_LO) * P2);
        dense[i] = tab[(size_t)TSIZE + (h & HMASK)];        // level 1
    }
}

// ---------------- K_fine: hard-phased gather, levels 7..15 -> ws ----------------
// 16 gathers (2 points) issued back-to-back per wave before any dependent
// arithmetic: MLP 8->16. (256,8) pins VGPR<=64 so occupancy stays 8 waves/SIMD.
__global__ __launch_bounds__(256, 8) void gather_fine_kernel(
    const float* __restrict__ x,
    const float* __restrict__ tables,
    f32x2* __restrict__ ws,          // [9][npoints] float2
    int npoints, int levelShift)
{
    const int level = 7 + (blockIdx.x >> levelShift);        // slow index -> phases
    const int chunk = blockIdx.x & ((1 << levelShift) - 1);
    const float halfr = 0.5f * RES_C[level];

    const float2* __restrict__ tab = (const float2*)tables + (size_t)level * TSIZE;
    f32x2* __restrict__ wrow = ws + (size_t)(level - 7) * npoints;

    const int pA = chunk * 512 + threadIdx.x;
    const int pB = pA + 256;

    if (pB < npoints) {
        const float axv = (x[3 * pA + 0] + 1.0f);
        const float ayv = (x[3 * pA + 1] + 1.0f);
        const float azv = (x[3 * pA + 2] + 1.0f);
        const float bxv = (x[3 * pB + 0] + 1.0f);
        const float byv = (x[3 * pB + 1] + 1.0f);
        const float bzv = (x[3 * pB + 2] + 1.0f);

        unsigned hA[8], hB[8];
        float wxA, wyA, wzA, wxB, wyB, wzB;
        hash_corners(halfr, axv, ayv, azv, hA, wxA, wyA, wzA);
        hash_corners(halfr, bxv, byv, bzv, hB, wxB, wyB, wzB);

        float2 vA[8], vB[8];
#pragma unroll
        for (int i = 0; i < 8; ++i) vA[i] = tab[hA[i]];
#pragma unroll
        for (int i = 0; i < 8; ++i) vB[i] = tab[hB[i]];

        const f32x2 rA = trilerp(vA, wxA, wyA, wzA);
        const f32x2 rB = trilerp(vB, wxB, wyB, wzB);
        wrow[pA] = rA;    // plain: L2 -> Infinity Cache (R2's proven win)
        wrow[pB] = rB;
    } else if (pA < npoints) {
        unsigned hA[8]; float wxA, wyA, wzA;
        hash_corners(halfr, x[3 * pA + 0] + 1.0f, x[3 * pA + 1] + 1.0f,
                     x[3 * pA + 2] + 1.0f, hA, wxA, wyA, wzA);
        float2 vA[8];
#pragma unroll
        for (int i = 0; i < 8; ++i) vA[i] = tab[hA[i]];
        wrow[pA] = trilerp(vA, wxA, wyA, wzA);
    }
}

// ---------------- K_final: l0-1 LDS + l2-6 global + l7-15 ws -> out ----------------
__global__ __launch_bounds__(256) void final_kernel(
    const float* __restrict__ x,
    const float* __restrict__ tables,
    const f32x2* __restrict__ ws,    // [9][npoints] float2
    const float2* __restrict__ dense_ws,
    float* __restrict__ out,
    int npoints)
{
    // union: phase 1 = 2060 float2 dense stage (16480B); phase 2 = 256x17 tile
    __shared__ float smem[4352];     // 17408 B -> 8 blocks/CU

    const int t = threadIdx.x;
    const int base = blockIdx.x * 256;

    // stage dense levels 0-1 (coalesced; source is L2/IC-hot after first blocks)
    {
        float2* sd = (float2*)smem;
        for (int i = t; i < NDENSE; i += 256)
            sd[i] = dense_ws[i];
    }
    __syncthreads();

    if (base + 256 <= npoints) {
        const int p = base + t;
        const float px = x[3 * p + 0] + 1.0f;
        const float py = x[3 * p + 1] + 1.0f;
        const float pz = x[3 * p + 2] + 1.0f;

        // issue the 9 independent ws stream-reads FIRST so their latency
        // overlaps the l2-6 gathers below
        f32x2 wsv[9];
#pragma unroll
        for (int li = 0; li < 9; ++li)
            wsv[li] = __builtin_nontemporal_load(ws + (size_t)li * npoints + p);

        float acc[32];
        const float2* __restrict__ sd = (const float2*)smem;

        // levels 0,1 from LDS dense copies
        dense_lerp(sd,       L0_LO, L0_DIM, px * 8.0f,  py * 8.0f,  pz * 8.0f,
                   acc[0], acc[1]);
        dense_lerp(sd + 729, L1_LO, L1_DIM, px * 10.0f, py * 10.0f, pz * 10.0f,
                   acc[2], acc[3]);

        // levels 2..6 global hashed gathers (footprints 0.17-2.2MB, union
        // ~4.4MB ~ one XCD L2 -> soft-phase safe)
#pragma unroll
        for (int l = 2; l < 7; ++l) {
            const float halfr = 0.5f * RES_C[l];
            const float2* __restrict__ tab = (const float2*)tables + (size_t)l * TSIZE;
            gather_lerp(tab, px * halfr, py * halfr, pz * halfr,
                        acc[2 * l], acc[2 * l + 1]);
        }

#pragma unroll
        for (int li = 0; li < 9; ++li) {
            acc[14 + 2 * li]     = wsv[li].x;
            acc[14 + 2 * li + 1] = wsv[li].y;
        }

        __syncthreads();   // done reading sdense; reuse smem as transpose tile

        // ---- line 0: levels 0-7 (floats 0..15 of the out row) ----
#pragma unroll
        for (int i = 0; i < 16; ++i)
            smem[t * 17 + i] = acc[i];
        __syncthreads();
        {
            float* obase = out + (size_t)base * 32;
#pragma unroll
            for (int k = 0; k < 4; ++k) {
                const int s  = k * 256 + t;
                const int pt = s >> 2;
                const int c  = s & 3;
                f32x4 q = { smem[pt * 17 + 4 * c + 0], smem[pt * 17 + 4 * c + 1],
                            smem[pt * 17 + 4 * c + 2], smem[pt * 17 + 4 * c + 3] };
                __builtin_nontemporal_store(q, (f32x4*)(obase + (size_t)pt * 32 + 4 * c));
            }
        }
        __syncthreads();

        // ---- line 1: levels 8-15 (floats 16..31) ----
#pragma unroll
        for (int i = 0; i < 16; ++i)
            smem[t * 17 + i] = acc[16 + i];
        __syncthreads();
        {
            float* obase = out + (size_t)base * 32 + 16;
#pragma unroll
            for (int k = 0; k < 4; ++k) {
                const int s  = k * 256 + t;
                const int pt = s >> 2;
                const int c  = s & 3;
                f32x4 q = { smem[pt * 17 + 4 * c + 0], smem[pt * 17 + 4 * c + 1],
                            smem[pt * 17 + 4 * c + 2], smem[pt * 17 + 4 * c + 3] };
                __builtin_nontemporal_store(q, (f32x4*)(obase + (size_t)pt * 32 + 4 * c));
            }
        }
    } else {
        // tail (not taken at npoints = 2^20; kept for safety)
        const int p = base + t;
        if (p < npoints) {
            const float px = x[3 * p + 0] + 1.0f;
            const float py = x[3 * p + 1] + 1.0f;
            const float pz = x[3 * p + 2] + 1.0f;
            float acc[32];
            const float2* __restrict__ sd = (const float2*)smem;
            dense_lerp(sd,       L0_LO, L0_DIM, px * 8.0f,  py * 8.0f,  pz * 8.0f,
                       acc[0], acc[1]);
            dense_lerp(sd + 729, L1_LO, L1_DIM, px * 10.0f, py * 10.0f, pz * 10.0f,
                       acc[2], acc[3]);
#pragma unroll
            for (int l = 2; l < 7; ++l) {
                const float halfr = 0.5f * RES_C[l];
                const float2* __restrict__ tab = (const float2*)tables + (size_t)l * TSIZE;
                gather_lerp(tab, px * halfr, py * halfr, pz * halfr,
                            acc[2 * l], acc[2 * l + 1]);
            }
#pragma unroll
            for (int li = 0; li < 9; ++li) {
                f32x2 v = ws[(size_t)li * npoints + p];
                acc[14 + 2 * li]     = v.x;
                acc[14 + 2 * li + 1] = v.y;
            }
            float* orow = out + (size_t)p * 32;
#pragma unroll
            for (int i = 0; i < 8; ++i) {
                f32x4 v = { acc[4 * i + 0], acc[4 * i + 1], acc[4 * i + 2], acc[4 * i + 3] };
                *(f32x4*)(orow + 4 * i) = v;
            }
        }
    }
}

// ---------------- Fallback if ws too small (all 16 levels, one pass) ----------------
__global__ __launch_bounds__(256) void hashgrid_fallback_kernel(
    const float* __restrict__ x,
    const float* __restrict__ tables,
    float* __restrict__ out)
{
    const int p = blockIdx.x * 256 + threadIdx.x;

    const float px = x[3 * p + 0] + 1.0f;
    const float py = x[3 * p + 1] + 1.0f;
    const float pz = x[3 * p + 2] + 1.0f;

    float acc[32];
    const float2* __restrict__ tab = (const float2*)tables;

#pragma unroll
    for (int l = 0; l < 16; ++l) {
        const float halfr = 0.5f * RES_C[l];
        float ra, rb;
        gather_lerp(tab + (size_t)l * TSIZE, px * halfr, py * halfr, pz * halfr, ra, rb);
        acc[2 * l + 0] = ra;
        acc[2 * l + 1] = rb;
    }

    f32x4* orow = (f32x4*)(out + (size_t)p * 32);
#pragma unroll
    for (int i = 0; i < 8; ++i) {
        f32x4 v = { acc[4 * i + 0], acc[4 * i + 1], acc[4 * i + 2], acc[4 * i + 3] };
        orow[i] = v;
    }
}

extern "C" void kernel_launch(void* const* d_in, const int* in_sizes, int n_in,
                              void* d_out, int out_size, void* d_ws, size_t ws_size,
                              hipStream_t stream) {
    const float* x      = (const float*)d_in[0];
    const float* tables = (const float*)d_in[1];
    float* out          = (float*)d_out;

    const int npoints = in_sizes[0] / 3;                       // 1048576
    const size_t fine_bytes = (size_t)9 * npoints * sizeof(float2);  // 72 MB
    const size_t ws_needed  = fine_bytes + NDENSE * sizeof(float2);

    if (ws_size >= ws_needed) {
        f32x2*  ws_fine  = (f32x2*)d_ws;
        float2* dense_ws = (float2*)((char*)d_ws + fine_bytes);

        hipLaunchKernelGGL(prep_dense_kernel, dim3((NDENSE + 255) / 256), dim3(256),
                           0, stream, tables, dense_ws);

        int chunks = (npoints + 511) / 512;
        int levelShift = 0;
        while ((1 << levelShift) < chunks) ++levelShift;
        hipLaunchKernelGGL(gather_fine_kernel, dim3(9 << levelShift), dim3(256),
                           0, stream, x, tables, ws_fine, npoints, levelShift);

        hipLaunchKernelGGL(final_kernel, dim3((npoints + 255) / 256), dim3(256),
                           0, stream, x, tables, ws_fine, dense_ws, out, npoints);
    } else {
        hipLaunchKernelGGL(hashgrid_fallback_kernel, dim3((npoints + 255) / 256),
                           dim3(256), 0, stream, x, tables, out);
    }
}

// Round 7
// 489.501 us; speedup vs baseline: 1.0829x; 1.0829x over previous
//
#include <hip/hip_runtime.h>

// Round-10. R6 post-mortem: MLP increase was compiler-defeated (VGPR=28 can't
// hold 16 float2 in flight) and the rate data shows the fine gather sits at
// 0.437 line-req/cyc/CU = ~87% of the L2 tag-lookup cap (16 chan/XCD x 8 XCD
// = 0.5/CU/cyc). Request-COUNT bound -> cut requests instead of raising MLP:
// de-hash mid levels into DENSE [iz][iy][ix] vertex tables in ws (prep
// kernel). Dense x-pair corners are address-adjacent -> MSHR merges them ->
// 4.5 line-req/point instead of 8. Dense l8-10 stay in the hard-phased fine
// kernel (tables 1.1/2.2/4.6MB ~ XCD L2); l2-7 dense move into final (tiny,
// L1/L2-hot); l0-1 dense staged in LDS. l11-15 stay hashed+phased (dense too
// big / IC-thrash risk). Dense grids padded +1 coord so the fp edge
// (ix+1 = res+1) stays in-bounds and reference-exact.

#define TSIZE (1u << 19)
#define HMASK (TSIZE - 1u)
#define P1 2654435761u
#define P2 805459861u

typedef float f32x4 __attribute__((ext_vector_type(4)));
typedef float f32x2 __attribute__((ext_vector_type(2)));

__constant__ float RES_C[16] = {16.f, 20.f, 25.f, 32.f, 40.f, 50.f, 64.f, 80.f,
                                101.f, 128.f, 161.f, 203.f, 256.f, 322.f, 406.f, 512.f};

// dense geometry, levels 0..10: lo = floor(res/2), dim = res - lo + 2 (pad +1)
__constant__ int LO_C[11]  = {8, 10, 12, 16, 20, 25, 32, 40, 50, 64, 80};
__constant__ int DIM_C[11] = {10, 12, 15, 18, 22, 27, 34, 42, 53, 66, 83};
__constant__ int OFF_C[11] = {0, 1000, 2728, 6103, 11935, 22583,
                              42266, 81570, 155658, 304535, 592031};
#define NDENSE_TOT 1163818   // sum of DIM^3, float2 entries (9.3 MB)
#define NDENSE01   2728      // l0+l1 entries staged in LDS (21.8 KB)

// v order: 000,001,010,011,100,101,110,111 (x-major pairs v[i],v[i+4])
__device__ __forceinline__ f32x2 trilerp(const float2 v[8],
                                         const float wx, const float wy, const float wz)
{
    const float c00a = v[0].x + wx * (v[4].x - v[0].x);
    const float c00b = v[0].y + wx * (v[4].y - v[0].y);
    const float c01a = v[1].x + wx * (v[5].x - v[1].x);
    const float c01b = v[1].y + wx * (v[5].y - v[1].y);
    const float c10a = v[2].x + wx * (v[6].x - v[2].x);
    const float c10b = v[2].y + wx * (v[6].y - v[2].y);
    const float c11a = v[3].x + wx * (v[7].x - v[3].x);
    const float c11b = v[3].y + wx * (v[7].y - v[3].y);

    const float c0a = c00a + wy * (c10a - c00a);
    const float c0b = c00b + wy * (c10b - c00b);
    const float c1a = c01a + wy * (c11a - c01a);
    const float c1b = c01b + wy * (c11b - c01b);

    f32x2 r = { c0a + wz * (c1a - c0a), c0b + wz * (c1b - c0b) };
    return r;
}

// hashed gather (fx etc pre-scaled by caller)
__device__ __forceinline__ f32x2 gather_lerp(const float2* __restrict__ tab,
                                             const float fx, const float fy, const float fz)
{
    const float bx = floorf(fx), by = floorf(fy), bz = floorf(fz);
    const float wx = fx - bx, wy = fy - by, wz = fz - bz;

    const unsigned ix0 = (unsigned)(int)bx;
    const unsigned iy0 = (unsigned)(int)by * P1;
    const unsigned iz0 = (unsigned)(int)bz * P2;
    const unsigned ix1 = ix0 + 1u, iy1 = iy0 + P1, iz1 = iz0 + P2;

    float2 v[8];
    v[0] = tab[(ix0 ^ iy0 ^ iz0) & HMASK];
    v[1] = tab[(ix0 ^ iy0 ^ iz1) & HMASK];
    v[2] = tab[(ix0 ^ iy1 ^ iz0) & HMASK];
    v[3] = tab[(ix0 ^ iy1 ^ iz1) & HMASK];
    v[4] = tab[(ix1 ^ iy0 ^ iz0) & HMASK];
    v[5] = tab[(ix1 ^ iy0 ^ iz1) & HMASK];
    v[6] = tab[(ix1 ^ iy1 ^ iz0) & HMASK];
    v[7] = tab[(ix1 ^ iy1 ^ iz1) & HMASK];
    return trilerp(v, fx - bx, fy - by, fz - bz);
}

// dense gather: [iz][iy][ix] layout; x-pairs adjacent -> MSHR line merge
__device__ __forceinline__ f32x2 dense_lerp(const float2* __restrict__ base,
                                            const int lo, const int d,
                                            const float fx, const float fy, const float fz)
{
    const float bx = floorf(fx), by = floorf(fy), bz = floorf(fz);
    const float wx = fx - bx, wy = fy - by, wz = fz - bz;
    const int ix = (int)bx - lo, iy = (int)by - lo, iz = (int)bz - lo;
    const float2* p = base + ((size_t)(iz * d + iy) * d + ix);
    const int dd = d * d;

    float2 v[8];
    v[0] = p[0];        v[4] = p[1];        // x-pair, same 64B line 7/8 of the time
    v[2] = p[d];        v[6] = p[d + 1];
    v[1] = p[dd];       v[5] = p[dd + 1];
    v[3] = p[dd + d];   v[7] = p[dd + d + 1];
    return trilerp(v, wx, wy, wz);
}

// ---------------- prep: de-hash levels 0..10 into dense ws tables ----------------
__global__ __launch_bounds__(256) void prep_dense_kernel(
    const float* __restrict__ tables, float2* __restrict__ dense)
{
    const int i = blockIdx.x * 256 + threadIdx.x;
    if (i >= NDENSE_TOT) return;

    int l = 0;
#pragma unroll
    for (int k = 1; k < 11; ++k) l += (i >= OFF_C[k]);

    const int r  = i - OFF_C[l];
    const int d  = DIM_C[l];
    const int lo = LO_C[l];
    const int d2 = d * d;
    const int iz = r / d2;
    const int rm = r - iz * d2;
    const int iy = rm / d;
    const int ix = rm - iy * d;

    const unsigned h = ((unsigned)(ix + lo)) ^
                       ((unsigned)(iy + lo) * P1) ^
                       ((unsigned)(iz + lo) * P2);
    dense[i] = ((const float2*)tables)[(size_t)l * TSIZE + (h & HMASK)];
}

// ---------------- K_fine: hard-phased, levels 8..15 -> ws ----------------
// R5's proven 2-batch q-loop structure (VGPR ~20-28, occ ~87%).
__global__ __launch_bounds__(256) void gather_fine_kernel(
    const float* __restrict__ x,
    const float* __restrict__ tables,
    const float2* __restrict__ dense,
    f32x2* __restrict__ ws,          // [8][npoints] float2
    int npoints, int levelShift)
{
    const int level = 8 + (blockIdx.x >> levelShift);        // slow index -> phases
    const int chunk = blockIdx.x & ((1 << levelShift) - 1);
    const float halfr = 0.5f * RES_C[level];

    const bool isDense = (level <= 10);
    const float2* __restrict__ tab  = (const float2*)tables + (size_t)level * TSIZE;
    const float2* __restrict__ tabd = dense + (isDense ? OFF_C[level] : 0);
    const int lo = isDense ? LO_C[level] : 0;
    const int d  = isDense ? DIM_C[level] : 1;

    f32x2* __restrict__ wrow = ws + (size_t)(level - 8) * npoints;

#pragma unroll
    for (int q = 0; q < 2; ++q) {
        const int p = chunk * 512 + q * 256 + threadIdx.x;
        if (p >= npoints) break;

        const float fx = (x[3 * p + 0] + 1.0f) * halfr;
        const float fy = (x[3 * p + 1] + 1.0f) * halfr;
        const float fz = (x[3 * p + 2] + 1.0f) * halfr;

        f32x2 r;
        if (isDense) r = dense_lerp(tabd, lo, d, fx, fy, fz);   // wave-uniform branch
        else         r = gather_lerp(tab, fx, fy, fz);

        wrow[p] = r;    // plain: L2 -> Infinity Cache (R2's proven win)
    }
}

// ---------------- K_final: l0-1 LDS + l2-7 dense + l8-15 ws -> out ----------------
__global__ __launch_bounds__(256) void final_kernel(
    const float* __restrict__ x,
    const f32x2* __restrict__ ws,    // [8][npoints] float2
    const float2* __restrict__ dense,
    float* __restrict__ out,
    int npoints)
{
    // phase 1: 2728 float2 dense l0-1 stage (21824B); phase 2: 256x17 tile (17408B)
    __shared__ float smem[5456];

    const int t = threadIdx.x;
    const int base = blockIdx.x * 256;

    {   // stage dense levels 0-1 (coalesced; L2/IC-hot after first blocks)
        float2* sd = (float2*)smem;
        for (int i = t; i < NDENSE01; i += 256)
            sd[i] = dense[i];
    }
    __syncthreads();

    if (base + 256 <= npoints) {
        const int p = base + t;
        const float px = x[3 * p + 0] + 1.0f;
        const float py = x[3 * p + 1] + 1.0f;
        const float pz = x[3 * p + 2] + 1.0f;

        // issue the 8 independent ws stream-reads FIRST to overlap the gathers
        f32x2 wsv[8];
#pragma unroll
        for (int li = 0; li < 8; ++li)
            wsv[li] = __builtin_nontemporal_load(ws + (size_t)li * npoints + p);

        float acc[32];
        const float2* __restrict__ sd = (const float2*)smem;

        // levels 0,1 from LDS dense copies
        {
            f32x2 r0 = dense_lerp(sd,        8, 10, px * 8.0f,  py * 8.0f,  pz * 8.0f);
            f32x2 r1 = dense_lerp(sd + 1000, 10, 12, px * 10.0f, py * 10.0f, pz * 10.0f);
            acc[0] = r0.x; acc[1] = r0.y; acc[2] = r1.x; acc[3] = r1.y;
        }

        // levels 2..7 from global dense tables (22KB..580KB: L1/L2-hot)
#pragma unroll
        for (int l = 2; l < 8; ++l) {
            const float halfr = 0.5f * RES_C[l];
            f32x2 r = dense_lerp(dense + OFF_C[l], LO_C[l], DIM_C[l],
                                 px * halfr, py * halfr, pz * halfr);
            acc[2 * l] = r.x; acc[2 * l + 1] = r.y;
        }

#pragma unroll
        for (int li = 0; li < 8; ++li) {
            acc[16 + 2 * li]     = wsv[li].x;
            acc[16 + 2 * li + 1] = wsv[li].y;
        }

        __syncthreads();   // done reading the dense stage; reuse smem as tile

        // ---- line 0: levels 0-7 (floats 0..15 of the out row) ----
#pragma unroll
        for (int i = 0; i < 16; ++i)
            smem[t * 17 + i] = acc[i];
        __syncthreads();
        {
            float* obase = out + (size_t)base * 32;
#pragma unroll
            for (int k = 0; k < 4; ++k) {
                const int s  = k * 256 + t;
                const int pt = s >> 2;
                const int c  = s & 3;
                f32x4 q = { smem[pt * 17 + 4 * c + 0], smem[pt * 17 + 4 * c + 1],
                            smem[pt * 17 + 4 * c + 2], smem[pt * 17 + 4 * c + 3] };
                __builtin_nontemporal_store(q, (f32x4*)(obase + (size_t)pt * 32 + 4 * c));
            }
        }
        __syncthreads();

        // ---- line 1: levels 8-15 (floats 16..31) ----
#pragma unroll
        for (int i = 0; i < 16; ++i)
            smem[t * 17 + i] = acc[16 + i];
        __syncthreads();
        {
            float* obase = out + (size_t)base * 32 + 16;
#pragma unroll
            for (int k = 0; k < 4; ++k) {
                const int s  = k * 256 + t;
                const int pt = s >> 2;
                const int c  = s & 3;
                f32x4 q = { smem[pt * 17 + 4 * c + 0], smem[pt * 17 + 4 * c + 1],
                            smem[pt * 17 + 4 * c + 2], smem[pt * 17 + 4 * c + 3] };
                __builtin_nontemporal_store(q, (f32x4*)(obase + (size_t)pt * 32 + 4 * c));
            }
        }
    } else {
        // tail (not taken at npoints = 2^20; kept for safety)
        const int p = base + t;
        if (p < npoints) {
            const float px = x[3 * p + 0] + 1.0f;
            const float py = x[3 * p + 1] + 1.0f;
            const float pz = x[3 * p + 2] + 1.0f;
            float acc[32];
            const float2* __restrict__ sd = (const float2*)smem;
            f32x2 r0 = dense_lerp(sd,        8, 10, px * 8.0f,  py * 8.0f,  pz * 8.0f);
            f32x2 r1 = dense_lerp(sd + 1000, 10, 12, px * 10.0f, py * 10.0f, pz * 10.0f);
            acc[0] = r0.x; acc[1] = r0.y; acc[2] = r1.x; acc[3] = r1.y;
#pragma unroll
            for (int l = 2; l < 8; ++l) {
                const float halfr = 0.5f * RES_C[l];
                f32x2 r = dense_lerp(dense + OFF_C[l], LO_C[l], DIM_C[l],
                                     px * halfr, py * halfr, pz * halfr);
                acc[2 * l] = r.x; acc[2 * l + 1] = r.y;
            }
#pragma unroll
            for (int li = 0; li < 8; ++li) {
                f32x2 v = ws[(size_t)li * npoints + p];
                acc[16 + 2 * li]     = v.x;
                acc[16 + 2 * li + 1] = v.y;
            }
            float* orow = out + (size_t)p * 32;
#pragma unroll
            for (int i = 0; i < 8; ++i) {
                f32x4 v = { acc[4 * i + 0], acc[4 * i + 1], acc[4 * i + 2], acc[4 * i + 3] };
                *(f32x4*)(orow + 4 * i) = v;
            }
        }
    }
}

// ---------------- Fallback if ws too small (all 16 levels hashed) ----------------
__global__ __launch_bounds__(256) void hashgrid_fallback_kernel(
    const float* __restrict__ x,
    const float* __restrict__ tables,
    float* __restrict__ out)
{
    const int p = blockIdx.x * 256 + threadIdx.x;

    const float px = x[3 * p + 0] + 1.0f;
    const float py = x[3 * p + 1] + 1.0f;
    const float pz = x[3 * p + 2] + 1.0f;

    float acc[32];
    const float2* __restrict__ tab = (const float2*)tables;

#pragma unroll
    for (int l = 0; l < 16; ++l) {
        const float halfr = 0.5f * RES_C[l];
        f32x2 r = gather_lerp(tab + (size_t)l * TSIZE,
                              px * halfr, py * halfr, pz * halfr);
        acc[2 * l + 0] = r.x;
        acc[2 * l + 1] = r.y;
    }

    f32x4* orow = (f32x4*)(out + (size_t)p * 32);
#pragma unroll
    for (int i = 0; i < 8; ++i) {
        f32x4 v = { acc[4 * i + 0], acc[4 * i + 1], acc[4 * i + 2], acc[4 * i + 3] };
        orow[i] = v;
    }
}

extern "C" void kernel_launch(void* const* d_in, const int* in_sizes, int n_in,
                              void* d_out, int out_size, void* d_ws, size_t ws_size,
                              hipStream_t stream) {
    const float* x      = (const float*)d_in[0];
    const float* tables = (const float*)d_in[1];
    float* out          = (float*)d_out;

    const int npoints = in_sizes[0] / 3;                       // 1048576
    const size_t fine_bytes = (size_t)8 * npoints * sizeof(float2);  // 64 MB
    const size_t ws_needed  = fine_bytes + (size_t)NDENSE_TOT * sizeof(float2);

    if (ws_size >= ws_needed) {
        f32x2*  ws_fine = (f32x2*)d_ws;
        float2* dense   = (float2*)((char*)d_ws + fine_bytes);

        hipLaunchKernelGGL(prep_dense_kernel,
                           dim3((NDENSE_TOT + 255) / 256), dim3(256), 0, stream,
                           tables, dense);

        int chunks = (npoints + 511) / 512;
        int levelShift = 0;
        while ((1 << levelShift) < chunks) ++levelShift;
        hipLaunchKernelGGL(gather_fine_kernel, dim3(8 << levelShift), dim3(256),
                           0, stream, x, tables, dense, ws_fine, npoints, levelShift);

        hipLaunchKernelGGL(final_kernel, dim3((npoints + 255) / 256), dim3(256),
                           0, stream, x, ws_fine, dense, out, npoints);
    } else {
        hipLaunchKernelGGL(hashgrid_fallback_kernel, dim3((npoints + 255) / 256),
                           dim3(256), 0, stream, x, tables, out);
    }
}